// Round 16
// baseline (147.771 us; speedup 1.0000x reference)
//
#include <hip/hip_runtime.h>
#include <stdint.h>

// Multi-head Hyena conv, MFMA flash-attention form, round 26:
//   S^T[m][l] = sum_d1 v[d1,m]*x1[d1,l]       mfma 16x16x16 (K=8 valid)
//   P[l][m]   = S * k[l-m]   (sliding f32x4 gate window, zero => causal)
//   O^T[d2][l] += x2 . P^T                    mfma 16x16x32 (full K=32)
// Round-26: 2-DEEP STAGING PIPELINE on r20 base (r25 swizzle REVERTED:
// prediction failed -- conflicts 2.72M->4.98M yet time neutral => gwin
// conflicts not on critical path AND my bank model wrong; lever closed).
// Hypothesis: pack-stall. Issue utilization ~12% (80 inst/iter x 272
// wave-iters vs 170K cyc wall) -> machine mostly waits. Stage loads are
// issued 1 compute-phase (~500-700cyc) before use; HBM latency ~900cyc
// (m126) => every chunk-top pack stalls 200-400cyc, x8.5 chunks, waves
// lockstep. Fix: two named stage-reg sets A/B; chunk n packs set n&1
// (loaded TWO chunks ago, ~1400cyc in flight) and issues chunk n+2 into
// the same set. Buffer p = n&1 == set => packA->buf0, packB->buf1.
// Gate-file carry identity holds across chunks (unchanged). Cost: +20
// long-lived scalar regs (est ~84-104 live, cap 128 -- r13 clean there;
// NOT the r14 straight-line S-liveness blowup).
// Tripwire: WRITE>25MB = spill -> void, revert to r20. Clean-neutral =>
// loads return within one chunk; declare structural plateau at r20.
// Carried (r20): (256,4), 16x16x16 S, dbuf vT/x2T/gwin + single barrier
// per chunk, carried gate file, rolling loop, v_pk_mul+v_perm gating.
// Shapes fixed by setup: B=2, D=1024, L=2048, NH=8, H=128.

typedef __attribute__((ext_vector_type(8))) short bf16x8;
typedef __attribute__((ext_vector_type(4))) short bf16x4;
typedef __attribute__((ext_vector_type(4))) float f32x4;
typedef __attribute__((ext_vector_type(2))) float f32x2;

#define NHd  8
#define SC   128     // m superchunk staged in LDS
#define GW   256     // gate window: l-m spans [l0b-s0-127, l0b-s0+127]

static __device__ __forceinline__ uint32_t pkbf(float a, float b) {
    // RNE-ish pack {bf16(a) lo, bf16(b) hi}; +0x8000 rounds (ties away)
    const uint32_t ua = __float_as_uint(a) + 0x8000u;
    const uint32_t ub = __float_as_uint(b) + 0x8000u;
    return __builtin_amdgcn_perm(ub, ua, 0x07060302u);
}

static __device__ __forceinline__ uint32_t pktr(f32x2 p) {
    // truncation pack: upper 16 bits of each f32 -> {lo,hi} bf16 (1 v_perm)
    union { f32x2 f; uint32_t u[2]; } c; c.f = p;
    return __builtin_amdgcn_perm(c.u[1], c.u[0], 0x07060302u);
}

// gate two S values by two k values: v_pk_mul_f32 + v_perm (2 inst)
static __device__ __forceinline__ uint32_t gmul2(f32x2 s, f32x2 g) {
    return pktr(s * g);
}

// S-MFMA: 16x16x16 bf16 (K=8 valid). Same C layout as 16x16x32 family.
static __device__ __forceinline__ f32x4 mfmaS(bf16x4 a, bf16x4 b, f32x4 c) {
#if __has_builtin(__builtin_amdgcn_mfma_f32_16x16x16bf16_1k)
    return __builtin_amdgcn_mfma_f32_16x16x16bf16_1k(a, b, c, 0, 0, 0);
#else
    f32x4 d;
    asm("v_mfma_f32_16x16x16_bf16 %0, %1, %2, %3"
        : "=v"(d) : "v"(a), "v"(b), "v"(c));
    return d;
#endif
}

union U8 { uint32_t u[4]; bf16x8 v; uint4 q; };
union U4 { uint32_t u[2]; bf16x4 v; };

__global__ __launch_bounds__(256, 4) void hyena_mfma26_kernel(
    const float* __restrict__ v, const float* __restrict__ kf,
    const float* __restrict__ bias, const float* __restrict__ x1,
    const float* __restrict__ x2, float* __restrict__ out,
    int B, int H, int L)
{
    __shared__ __align__(16) float4 gwin[2][GW];         // dbuf gate window
    __shared__ __align__(16) ushort vT[2][2][SC][NHd];   // [buf][b][m][d1]
    __shared__ __align__(16) ushort x2T[2][2][NHd][136]; // [buf][b][d2][pi(m)]
    __shared__ float sbuf[2][128];                       // skip gate per (b,l)

    const int tid  = threadIdx.x;
    const int h    = blockIdx.x;
    const int l0b  = ((int)gridDim.y - 1 - (int)blockIdx.y) * 128; // big-l first
    const int nk   = l0b + 128;

    const int lane = tid & 63, wv = tid >> 6;
    const int lq   = lane & 15, quad = lane >> 4;
    const int wb   = wv & 1;                // batch handled by this wave
    const int wseg = wv >> 1;               // which 64-l half of the block
    const int wl0  = l0b + wseg * 64;       // wave's 64-l range start
    const int baseb = (wb * H + h) * NHd * L;

    // ---------- fixed staging coordinates ----------
    const int sb_b   = tid >> 7, sb_row = tid & 127;
    const int sb_bs  = (sb_b * H + h) * NHd * L;
    const float* vp0 = v + sb_bs + sb_row;
    const int sb_d2  = sb_row >> 4, sb_ms = (sb_row & 15) * 8;
    const int sb_G   = sb_ms & ~31;                 // 32-group base
    const int sb_o   = sb_ms & 31;                  // 0,8,16,24
    const int sb_pa  = ((sb_o >> 2) & 3) * 8 + (sb_o >> 4) * 4;
    const float* xp0 = x2 + sb_bs + sb_d2 * L + sb_ms;
    const float* kp  = kf + h * L;
    const int gi0    = l0b - 127 + tid;             // k idx of gwin[tid] @ s0=0

    // ---------- 2-deep async stage register sets (A: even chunks/buf0,
    // B: odd chunks/buf1; each in flight TWO chunk periods) ----------
    float  fvA0, fvA1, fvA2, fvA3, fvA4, fvA5, fvA6, fvA7;
    float4 qA0, qA1;
    float  kgA0 = 0.f, kgA1 = 0.f, kgA2 = 0.f, kgA3 = 0.f;
    float  fvB0, fvB1, fvB2, fvB3, fvB4, fvB5, fvB6, fvB7;
    float4 qB0, qB1;
    float  kgB0 = 0.f, kgB1 = 0.f, kgB2 = 0.f, kgB3 = 0.f;

    auto issueA = [&](int s0) {
        const float* vp = vp0 + s0;
        fvA0 = vp[0 * L]; fvA1 = vp[1 * L]; fvA2 = vp[2 * L]; fvA3 = vp[3 * L];
        fvA4 = vp[4 * L]; fvA5 = vp[5 * L]; fvA6 = vp[6 * L]; fvA7 = vp[7 * L];
        qA0 = *(const float4*)(xp0 + s0);
        qA1 = *(const float4*)(xp0 + s0 + 4);
        if (tid < GW - 1) {
            const int i = gi0 - s0;
            if (i >= 3) {
                kgA0 = kp[i]; kgA1 = kp[i - 1]; kgA2 = kp[i - 2]; kgA3 = kp[i - 3];
            } else {
                kgA0 = kgA1 = kgA2 = kgA3 = 0.f;
                if (i >= 0) kgA0 = kp[i];
                if (i >= 1) kgA1 = kp[i - 1];
                if (i >= 2) kgA2 = kp[i - 2];
            }
        }
    };
    auto issueB = [&](int s0) {
        const float* vp = vp0 + s0;
        fvB0 = vp[0 * L]; fvB1 = vp[1 * L]; fvB2 = vp[2 * L]; fvB3 = vp[3 * L];
        fvB4 = vp[4 * L]; fvB5 = vp[5 * L]; fvB6 = vp[6 * L]; fvB7 = vp[7 * L];
        qB0 = *(const float4*)(xp0 + s0);
        qB1 = *(const float4*)(xp0 + s0 + 4);
        if (tid < GW - 1) {
            const int i = gi0 - s0;
            if (i >= 3) {
                kgB0 = kp[i]; kgB1 = kp[i - 1]; kgB2 = kp[i - 2]; kgB3 = kp[i - 3];
            } else {
                kgB0 = kgB1 = kgB2 = kgB3 = 0.f;
                if (i >= 0) kgB0 = kp[i];
                if (i >= 1) kgB1 = kp[i - 1];
                if (i >= 2) kgB2 = kp[i - 2];
            }
        }
    };
    // pack set A -> buf 0 (even chunks); set B -> buf 1 (odd chunks)
    auto packA = [&]() {
        *(uint4*)&vT[0][sb_b][sb_row][0] = make_uint4(
            pkbf(fvA0, fvA1), pkbf(fvA2, fvA3), pkbf(fvA4, fvA5), pkbf(fvA6, fvA7));
        *(uint2*)&x2T[0][sb_b][sb_d2][sb_G + sb_pa] =
            make_uint2(pkbf(qA0.x, qA0.y), pkbf(qA0.z, qA0.w));
        *(uint2*)&x2T[0][sb_b][sb_d2][sb_G + sb_pa + 8] =
            make_uint2(pkbf(qA1.x, qA1.y), pkbf(qA1.z, qA1.w));
        if (tid < GW - 1)
            gwin[0][tid] = make_float4(kgA0, kgA1, kgA2, kgA3);
    };
    auto packB = [&]() {
        *(uint4*)&vT[1][sb_b][sb_row][0] = make_uint4(
            pkbf(fvB0, fvB1), pkbf(fvB2, fvB3), pkbf(fvB4, fvB5), pkbf(fvB6, fvB7));
        *(uint2*)&x2T[1][sb_b][sb_d2][sb_G + sb_pa] =
            make_uint2(pkbf(qB0.x, qB0.y), pkbf(qB0.z, qB0.w));
        *(uint2*)&x2T[1][sb_b][sb_d2][sb_G + sb_pa + 8] =
            make_uint2(pkbf(qB1.x, qB1.y), pkbf(qB1.z, qB1.w));
        if (tid < GW - 1)
            gwin[1][tid] = make_float4(kgB0, kgB1, kgB2, kgB3);
    };

    // ---------- prologue ----------
    issueA(0);                    // chunk 0 (flies under xf/sbuf build)
    if (SC < nk) issueB(SC);      // chunk 1 (flies under everything below)

    // xf fragments (S-MFMA B operand, 16x16x16: k=4*(lane>>4)+i) for 4
    // l-subtiles. Quads 0-1 carry d1 = 4*quad+t; quads 2-3 zero.
    bf16x4 xf[4] = {};
    if (quad < 2) {
#pragma unroll
        for (int j = 0; j < 4; ++j) {
            float a0[4];
#pragma unroll
            for (int t = 0; t < 4; ++t)
                a0[t] = x1[baseb + (4 * quad + t) * L + wl0 + 16 * j + lq];
            U4 u0;
            u0.u[0] = pkbf(a0[0], a0[1]);
            u0.u[1] = pkbf(a0[2], a0[3]);
            xf[j] = u0.v;
        }
    }

    // skip-term gate, both b, 128 l (all 256 threads)
    {
        const int bb = tid >> 7, l = tid & 127;
        const int bs = (bb * H + h) * NHd * L;
        float s = 0.f;
#pragma unroll
        for (int d1 = 0; d1 < NHd; ++d1)
            s += bias[h * NHd + d1] * x1[bs + d1 * L + l0b + l]
                                    * v [bs + d1 * L + l0b + l];
        sbuf[bb][l] = s;
    }

    f32x4 acc[4];
#pragma unroll
    for (int j = 0; j < 4; ++j) acc[j] = (f32x4){0.f, 0.f, 0.f, 0.f};

    const int wlmax = wl0 + 63;
    // gate window coordinate (s0-independent): e = ebase - c
    const int ebase = 127 + wseg * 64 + lq - 4 * quad;

    bool gfirst = true;
    float4 g0, g1, g2, g3, g4;   // 5-deep gate file; carries across s0 too

    for (int s0 = 0, n = 0; s0 < nk; s0 += SC, ++n) {
        const int p = n & 1;

        // ---- write-late: pack set p (loaded 2 chunks ago) -> buf p;
        // then re-arm set p with chunk n+2's loads (2 periods to fly).
        // WAR-safe vs other waves per r20 argument; register anti-dep
        // (pack reads fv*, issue overwrites) handled by in-order issue.
        if (p == 0) {
            packA();
            if (s0 + 2 * SC < nk) issueA(s0 + 2 * SC);
        } else {
            packB();
            if (s0 + 2 * SC < nk) issueB(s0 + 2 * SC);
        }

        // ---- single barrier: staging visible; global loads NOT drained ----
        asm volatile("s_waitcnt lgkmcnt(0)" ::: "memory");
        __builtin_amdgcn_s_barrier();

        // wave-uniform trip count, multiple of 32 (wseg0: 64 at diagonal)
        const int cmax = min(SC, wlmax - s0 + 1);
        for (int c = 0; c < cmax; c += 32) {
            const int e = ebase - c;

            // ---- loads first (independent) ----
            // A frag (16x16x16): row=lane&15, k=4*(lane>>4)+i -> quads 0-1
            // read d1 = 4*quad..4*quad+3 (8B each); quads 2-3 zero.
            bf16x4 av0 = {}, av1 = {};
            if (quad < 2) {
                av0 = *(const bf16x4*)&vT[p][wb][c + lq][quad * 4];
                av1 = *(const bf16x4*)&vT[p][wb][c + 16 + lq][quad * 4];
            }
            // gate file: subtile j: lo = g(e+16j), hi = g(e+16j-16)
            if (gfirst) {
                g4 = *(const float4*)&gwin[p][e + 48];
                g3 = *(const float4*)&gwin[p][e + 32];
                g2 = *(const float4*)&gwin[p][e + 16];
                gfirst = false;
            } else { g4 = g2; g3 = g1; g2 = g0; }
            g1 = *(const float4*)&gwin[p][e];
            g0 = *(const float4*)&gwin[p][e - 16];
            const bf16x8 ax = *(const bf16x8*)&x2T[p][wb][lq & 7][c + 8 * quad];

            const f32x4 Z = {0.f, 0.f, 0.f, 0.f};
            // ---- subtile pair 0,1 ----
            {
                const f32x4 Sa0 = mfmaS(av0, xf[0], Z);
                const f32x4 Sa1 = mfmaS(av1, xf[0], Z);
                const f32x4 Sb0 = mfmaS(av0, xf[1], Z);
                const f32x4 Sb1 = mfmaS(av1, xf[1], Z);
                U8 p2;
                p2.u[0] = gmul2((f32x2){Sa0[0], Sa0[1]}, (f32x2){g1.x, g1.y});
                p2.u[1] = gmul2((f32x2){Sa0[2], Sa0[3]}, (f32x2){g1.z, g1.w});
                p2.u[2] = gmul2((f32x2){Sa1[0], Sa1[1]}, (f32x2){g0.x, g0.y});
                p2.u[3] = gmul2((f32x2){Sa1[2], Sa1[3]}, (f32x2){g0.z, g0.w});
                acc[0] = __builtin_amdgcn_mfma_f32_16x16x32_bf16(ax, p2.v, acc[0], 0, 0, 0);
                p2.u[0] = gmul2((f32x2){Sb0[0], Sb0[1]}, (f32x2){g2.x, g2.y});
                p2.u[1] = gmul2((f32x2){Sb0[2], Sb0[3]}, (f32x2){g2.z, g2.w});
                p2.u[2] = gmul2((f32x2){Sb1[0], Sb1[1]}, (f32x2){g1.x, g1.y});
                p2.u[3] = gmul2((f32x2){Sb1[2], Sb1[3]}, (f32x2){g1.z, g1.w});
                acc[1] = __builtin_amdgcn_mfma_f32_16x16x32_bf16(ax, p2.v, acc[1], 0, 0, 0);
            }
            // ---- subtile pair 2,3 ----
            {
                const f32x4 Sc0 = mfmaS(av0, xf[2], Z);
                const f32x4 Sc1 = mfmaS(av1, xf[2], Z);
                const f32x4 Sd0 = mfmaS(av0, xf[3], Z);
                const f32x4 Sd1 = mfmaS(av1, xf[3], Z);
                U8 p2;
                p2.u[0] = gmul2((f32x2){Sc0[0], Sc0[1]}, (f32x2){g3.x, g3.y});
                p2.u[1] = gmul2((f32x2){Sc0[2], Sc0[3]}, (f32x2){g3.z, g3.w});
                p2.u[2] = gmul2((f32x2){Sc1[0], Sc1[1]}, (f32x2){g2.x, g2.y});
                p2.u[3] = gmul2((f32x2){Sc1[2], Sc1[3]}, (f32x2){g2.z, g2.w});
                acc[2] = __builtin_amdgcn_mfma_f32_16x16x32_bf16(ax, p2.v, acc[2], 0, 0, 0);
                p2.u[0] = gmul2((f32x2){Sd0[0], Sd0[1]}, (f32x2){g4.x, g4.y});
                p2.u[1] = gmul2((f32x2){Sd0[2], Sd0[3]}, (f32x2){g4.z, g4.w});
                p2.u[2] = gmul2((f32x2){Sd1[0], Sd1[1]}, (f32x2){g3.x, g3.y});
                p2.u[3] = gmul2((f32x2){Sd1[2], Sd1[3]}, (f32x2){g3.z, g3.w});
                acc[3] = __builtin_amdgcn_mfma_f32_16x16x32_bf16(ax, p2.v, acc[3], 0, 0, 0);
            }
        }
    }

    // ---------- epilogue: O^T layout: lane (quad,lq): d2 = 4*quad+r, l = lq ----
    if (quad < 2) {
#pragma unroll
        for (int j = 0; j < 4; ++j) {
            const int lA  = wl0 + 16 * j + lq;
            const float sb = sbuf[wb][wseg * 64 + 16 * j + lq];
#pragma unroll
            for (int r = 0; r < 4; ++r) {
                const int ro = baseb + (4 * quad + r) * L + lA;
                out[ro] = acc[j][r] + x2[ro] * sb;
            }
        }
    }
}

extern "C" void kernel_launch(void* const* d_in, const int* in_sizes, int n_in,
                              void* d_out, int out_size, void* d_ws, size_t ws_size,
                              hipStream_t stream) {
    const float* v    = (const float*)d_in[0];
    const float* k    = (const float*)d_in[1];
    const float* bias = (const float*)d_in[2];
    const float* x1   = (const float*)d_in[3];
    const float* x2   = (const float*)d_in[4];
    float* out = (float*)d_out;

    const int D = in_sizes[2];            // 1024
    const int H = D / NHd;                // 128
    const int L = in_sizes[1] / H;        // 2048
    const int B = in_sizes[0] / (D * L);  // 2

    dim3 grid(H, L / 128);
    hyena_mfma26_kernel<<<grid, 256, 0, stream>>>(v, k, bias, x1, x2, out, B, H, L);
}